// Round 6
// baseline (160.317 us; speedup 1.0000x reference)
//
#include <hip/hip_runtime.h>

// SRL embeddings, fused single kernel — R8: champion (R2/R7) + Phase D
// 3-chain latency interleave. Shapes fixed: B=16,S=16,L=128,D=768,A=8,T=5.
//
// R7 control re-bench: 159.3 vs 158.6 -> noise is +-0.7us; R3-R6 regressions
// were real; champion geometry (CHUNK=32, BLOCK=256, 1536 blocks, fused
// Phase B) is a sharp local optimum. This round changes ONLY Phase D: the
// runtime-strided slot loop (j = r, r+8, r+16) serialized three dependent
// {LDS idx -> global load -> acc} chains per thread-group at every block's
// tail. Hand-unroll into three named chains, interleave loads in one i-loop
// -> 3 memory latencies collapse to ~1. Traffic/geometry/occupancy identical.

namespace {
constexpr int Bc = 16, Sc = 16, Lc = 128, Dc = 768, Ac = 8, Tc = 5;
constexpr int NF4    = Dc / 4;          // 192 float4 per row
constexpr int CHUNK  = 32;              // float4 columns per block
constexpr int NCHUNK = NF4 / CHUNK;     // 6
constexpr int BLOCK  = 256;             // 4 waves
constexpr int RP     = BLOCK / CHUNK;   // 8 l-phases
constexpr int NSLOT  = 3 * Ac;          // 24 arg slots (= 3 * RP exactly)
constexpr int OUT1   = Bc * Sc * NF4;       // sentence output, float4 units
constexpr int OUTG   = Bc * Sc * Ac * NF4;  // per-arg-type output, float4 units
}

__global__ __launch_bounds__(BLOCK) void srl_fused(
    const float4* __restrict__ hid,
    const int*    __restrict__ sids,
    const int*    __restrict__ amask,
    const int*    __restrict__ pids,
    const int*    __restrict__ a0ids,
    const int*    __restrict__ a1ids,
    float4*       __restrict__ out)
{
  const int c   = blockIdx.x;           // column chunk 0..5
  const int bs  = blockIdx.y;           // (b,s) 0..255
  const int tid = threadIdx.x;
  const int q   = tid & (CHUNK - 1);    // float4 column within chunk
  const int r   = tid >> 5;             // l-phase 0..7

  __shared__ int    sid[Lc];
  __shared__ short  slist[NSLOT][Lc];
  __shared__ int    scnt[NSLOT];
  __shared__ float4 red[BLOCK];

  // Phase A: stage sentence ids; prefix length via __syncthreads_count.
  int mval = 0;
  if (tid < Lc) {
    sid[tid] = sids[bs * Lc + tid];
    mval     = amask[bs * Lc + tid];
  }
  const int len = __syncthreads_count(mval != 0);

  const float4* __restrict__ hrow = hid + (size_t)bs * Lc * NF4 + c * CHUNK;

  // Phase B (lanes 0..23 of wave 0, overlapped with pooling on other waves):
  // count matches for all 5 tokens in one sid scan, pick LAST valid t
  // (tok!=0 && cnt>0), build its match list. (Match scan covers all 128
  // positions — reference applies no mask in _arg_embedding.)
  if (tid < NSLOT) {
    const int g = tid / Ac, a = tid % Ac;
    const int* ids = (g == 0 ? pids : (g == 1 ? a0ids : a1ids)) + (bs * Ac + a) * Tc;
    int tok[Tc], cnt[Tc];
#pragma unroll
    for (int t = 0; t < Tc; ++t) { tok[t] = ids[t]; cnt[t] = 0; }
    for (int l = 0; l < Lc; ++l) {
      const int v = sid[l];   // broadcast read
#pragma unroll
      for (int t = 0; t < Tc; ++t) cnt[t] += (v == tok[t]) ? 1 : 0;
    }
    int sel = 0, n = 0;
#pragma unroll
    for (int t = Tc - 1; t >= 0; --t) {
      if (n == 0 && tok[t] != 0 && cnt[t] > 0) { sel = tok[t]; n = cnt[t]; }
    }
    scnt[tid] = n;
    if (n > 0) {
      int k = 0;
      for (int l = 0; l < Lc; ++l)
        if (sid[l] == sel) slist[tid][k++] = (short)l;
    }
  }

  // Phase C: pooling partial sums over the valid prefix, l-split by r.
  float ax = 0.f, ay = 0.f, az = 0.f, aw = 0.f;
#pragma unroll 4
  for (int l = r; l < len; l += RP) {
    const float4 v = hrow[l * NF4 + q];
    ax += v.x; ay += v.y; az += v.z; aw += v.w;
  }
  red[tid] = make_float4(ax, ay, az, aw);
  __syncthreads();   // red ready; also publishes scnt/slist for Phase D

  // Phase C2: reduce the 8 l-phases, divide by len, write sentence embedding.
  if (tid < CHUNK) {
    float4 s = red[q];
#pragma unroll
    for (int p = 1; p < RP; ++p) {
      const float4 t = red[p * CHUNK + q];
      s.x += t.x; s.y += t.y; s.z += t.z; s.w += t.w;
    }
    const float inv = 1.0f / (float)(len > 0 ? len : 1);
    s.x *= inv; s.y *= inv; s.z *= inv; s.w *= inv;
    out[bs * NF4 + c * CHUNK + q] = s;
  }

  // Phase D: arg embeddings. Each 32-thread group r owns slots
  // {r, r+8, r+16}; the three dependency chains are interleaved in one
  // i-loop so their global loads issue together (1 latency, not 3).
  {
    const int j0 = r, j1 = r + RP, j2 = r + 2 * RP;
    const int n0 = scnt[j0], n1 = scnt[j1], n2 = scnt[j2];
    float ox0 = 0.f, oy0 = 0.f, oz0 = 0.f, ow0 = 0.f;
    float ox1 = 0.f, oy1 = 0.f, oz1 = 0.f, ow1 = 0.f;
    float ox2 = 0.f, oy2 = 0.f, oz2 = 0.f, ow2 = 0.f;
    const int nmax = max(n0, max(n1, n2));
    for (int i = 0; i < nmax; ++i) {
      if (i < n0) {
        const int l = (int)slist[j0][i];
        const float4 v = hrow[l * NF4 + q];
        ox0 += v.x; oy0 += v.y; oz0 += v.z; ow0 += v.w;
      }
      if (i < n1) {
        const int l = (int)slist[j1][i];
        const float4 v = hrow[l * NF4 + q];
        ox1 += v.x; oy1 += v.y; oz1 += v.z; ow1 += v.w;
      }
      if (i < n2) {
        const int l = (int)slist[j2][i];
        const float4 v = hrow[l * NF4 + q];
        ox2 += v.x; oy2 += v.y; oz2 += v.z; ow2 += v.w;
      }
    }
    if (n0 > 0) {
      const float inv = 1.0f / (float)n0;
      ox0 *= inv; oy0 *= inv; oz0 *= inv; ow0 *= inv;
    }
    if (n1 > 0) {
      const float inv = 1.0f / (float)n1;
      ox1 *= inv; oy1 *= inv; oz1 *= inv; ow1 *= inv;
    }
    if (n2 > 0) {
      const float inv = 1.0f / (float)n2;
      ox2 *= inv; oy2 *= inv; oz2 *= inv; ow2 *= inv;
    }
    // Stores: slot j -> group g = j>>3, arg a = j&7.
    out[OUT1 + (j0 >> 3) * OUTG + (bs * Ac + (j0 & 7)) * NF4 + c * CHUNK + q] =
        make_float4(ox0, oy0, oz0, ow0);
    out[OUT1 + (j1 >> 3) * OUTG + (bs * Ac + (j1 & 7)) * NF4 + c * CHUNK + q] =
        make_float4(ox1, oy1, oz1, ow1);
    out[OUT1 + (j2 >> 3) * OUTG + (bs * Ac + (j2 & 7)) * NF4 + c * CHUNK + q] =
        make_float4(ox2, oy2, oz2, ow2);
  }
}

extern "C" void kernel_launch(void* const* d_in, const int* in_sizes, int n_in,
                              void* d_out, int out_size, void* d_ws, size_t ws_size,
                              hipStream_t stream) {
  const float4* hid   = (const float4*)d_in[0];
  const int*    sids  = (const int*)d_in[1];
  const int*    amask = (const int*)d_in[2];
  const int*    pids  = (const int*)d_in[3];
  const int*    a0ids = (const int*)d_in[4];
  const int*    a1ids = (const int*)d_in[5];
  float4*       out   = (float4*)d_out;

  srl_fused<<<dim3(NCHUNK, Bc * Sc), dim3(BLOCK), 0, stream>>>(
      hid, sids, amask, pids, a0ids, a1ids, out);
}

// Round 7
// 160.021 us; speedup vs baseline: 1.0019x; 1.0019x over previous
//
#include <hip/hip_runtime.h>

// SRL embeddings, fused single kernel — R9: champion structure, CHUNK 32->64.
// Shapes fixed: B=16,S=16,L=128,D=768,A=8,T=5.
//
// Session ledger: R3(parallel scan) +11, R4(8-wave) +8, R5(split+CHUNK16) +13,
// R6(work-steal) +14, R7(control) +-0.7us noise, R8(Phase D ILP) neutral.
// The only large measured signal is slice geometry: CHUNK 32->16 cost +12us
// even with Phase B removed (R5) -> per-load-instruction segment size/count
// (2x512B at CHUNK=32, 4x256B at 16) drives stream efficiency. CHUNK=64 makes
// every wave load 1x1KiB fully contiguous (lane i -> base + 16B*i, the ideal
// coalescing pattern), halves Phase A/B replication (3 blocks per sentence),
// and keeps the proven 4-wave block + wave-0 Phase B overlap structure.
// Grid 768 blocks = 3/CU, 12 waves/CU (~48KB/CU in flight vs ~9KB needed).

namespace {
constexpr int Bc = 16, Sc = 16, Lc = 128, Dc = 768, Ac = 8, Tc = 5;
constexpr int NF4    = Dc / 4;          // 192 float4 per row
constexpr int CHUNK  = 64;              // float4 columns per block (1KiB slice)
constexpr int NCHUNK = NF4 / CHUNK;     // 3
constexpr int BLOCK  = 256;             // 4 waves
constexpr int RP     = BLOCK / CHUNK;   // 4 l-phases
constexpr int NSLOT  = 3 * Ac;          // 24 arg slots
constexpr int OUT1   = Bc * Sc * NF4;       // sentence output, float4 units
constexpr int OUTG   = Bc * Sc * Ac * NF4;  // per-arg-type output, float4 units
}

__global__ __launch_bounds__(BLOCK) void srl_fused(
    const float4* __restrict__ hid,
    const int*    __restrict__ sids,
    const int*    __restrict__ amask,
    const int*    __restrict__ pids,
    const int*    __restrict__ a0ids,
    const int*    __restrict__ a1ids,
    float4*       __restrict__ out)
{
  const int c   = blockIdx.x;           // column chunk 0..2
  const int bs  = blockIdx.y;           // (b,s) 0..255
  const int tid = threadIdx.x;
  const int q   = tid & (CHUNK - 1);    // float4 column within chunk (0..63)
  const int r   = tid >> 6;             // l-phase 0..3 (one wave per phase)

  __shared__ int    sid[Lc];
  __shared__ short  slist[NSLOT][Lc];
  __shared__ int    scnt[NSLOT];
  __shared__ float4 red[BLOCK];

  // Phase A: stage sentence ids; prefix length via __syncthreads_count.
  int mval = 0;
  if (tid < Lc) {
    sid[tid] = sids[bs * Lc + tid];
    mval     = amask[bs * Lc + tid];
  }
  const int len = __syncthreads_count(mval != 0);

  const float4* __restrict__ hrow = hid + (size_t)bs * Lc * NF4 + c * CHUNK;

  // Phase B (lanes 0..23 of wave 0, overlapped with pooling on waves 1..3):
  // count matches for all 5 tokens in one sid scan, pick LAST valid t
  // (tok!=0 && cnt>0), build its match list.
  if (tid < NSLOT) {
    const int g = tid / Ac, a = tid % Ac;
    const int* ids = (g == 0 ? pids : (g == 1 ? a0ids : a1ids)) + (bs * Ac + a) * Tc;
    int tok[Tc], cnt[Tc];
#pragma unroll
    for (int t = 0; t < Tc; ++t) { tok[t] = ids[t]; cnt[t] = 0; }
    for (int l = 0; l < Lc; ++l) {
      const int v = sid[l];   // broadcast read
#pragma unroll
      for (int t = 0; t < Tc; ++t) cnt[t] += (v == tok[t]) ? 1 : 0;
    }
    int sel = 0, n = 0;
#pragma unroll
    for (int t = Tc - 1; t >= 0; --t) {
      if (n == 0 && tok[t] != 0 && cnt[t] > 0) { sel = tok[t]; n = cnt[t]; }
    }
    scnt[tid] = n;
    if (n > 0) {
      int k = 0;
      for (int l = 0; l < Lc; ++l)
        if (sid[l] == sel) slist[tid][k++] = (short)l;
    }
  }

  // Phase C: pooling partial sums over the valid prefix, l-split by r.
  // Each wave load is 64 lanes x 16B = 1KiB contiguous (one row slice).
  float ax = 0.f, ay = 0.f, az = 0.f, aw = 0.f;
#pragma unroll 4
  for (int l = r; l < len; l += RP) {
    const float4 v = hrow[l * NF4 + q];
    ax += v.x; ay += v.y; az += v.z; aw += v.w;
  }
  red[tid] = make_float4(ax, ay, az, aw);
  __syncthreads();   // red ready; also publishes scnt/slist for Phase D

  // Phase C2: reduce the 4 l-phases, divide by len, write sentence embedding.
  if (tid < CHUNK) {
    float4 s = red[q];
#pragma unroll
    for (int p = 1; p < RP; ++p) {
      const float4 t = red[p * CHUNK + q];
      s.x += t.x; s.y += t.y; s.z += t.z; s.w += t.w;
    }
    const float inv = 1.0f / (float)(len > 0 ? len : 1);
    s.x *= inv; s.y *= inv; s.z *= inv; s.w *= inv;
    out[bs * NF4 + c * CHUNK + q] = s;
  }

  // Phase D: arg embeddings. 6 slots per wave (j = r, r+4, ..., r+20);
  // match rows hit L1/L2 (same columns streamed in Phase C).
  for (int j = r; j < NSLOT; j += RP) {
    const int n = scnt[j];
    float ox = 0.f, oy = 0.f, oz = 0.f, ow = 0.f;
    if (n > 0) {
      for (int i = 0; i < n; ++i) {
        const int l = (int)slist[j][i];   // broadcast read
        const float4 v = hrow[l * NF4 + q];
        ox += v.x; oy += v.y; oz += v.z; ow += v.w;
      }
      const float inv = 1.0f / (float)n;
      ox *= inv; oy *= inv; oz *= inv; ow *= inv;
    }
    const int g = j / Ac, a = j - g * Ac;
    out[OUT1 + g * OUTG + (bs * Ac + a) * NF4 + c * CHUNK + q] =
        make_float4(ox, oy, oz, ow);
  }
}

extern "C" void kernel_launch(void* const* d_in, const int* in_sizes, int n_in,
                              void* d_out, int out_size, void* d_ws, size_t ws_size,
                              hipStream_t stream) {
  const float4* hid   = (const float4*)d_in[0];
  const int*    sids  = (const int*)d_in[1];
  const int*    amask = (const int*)d_in[2];
  const int*    pids  = (const int*)d_in[3];
  const int*    a0ids = (const int*)d_in[4];
  const int*    a1ids = (const int*)d_in[5];
  float4*       out   = (float4*)d_out;

  srl_fused<<<dim3(NCHUNK, Bc * Sc), dim3(BLOCK), 0, stream>>>(
      hid, sids, amask, pids, a0ids, a1ids, out);
}